// Round 13
// baseline (80.736 us; speedup 1.0000x reference)
//
#include <hip/hip_runtime.h>

// Selective scan as truncated causal convolution (J=16 taps, absmax 0.0039
// stable across rounds 1-12), single fused kernel.
//
// R12->R13: the occupancy probe. Three paradigms (register streaming 62.5us,
// 2-deep DMA ring 64.5, 3-deep ring 66.7) all plateau at <=47% occupancy and
// <=4 TB/s. This version maximizes raw memory-level parallelism:
//  - fully fused (no h-kernel prelude, no d_ws at all)
//  - ZERO barriers in the conv loop: per-wave-private t-strips (TW=64),
//    halo re-read from global (23%, L3-absorbed)
//  - 256-thread blocks, ~88 VGPR -> ~22 waves/CU resident
//  - per chunk: 8 independent dwordx2 loads in flight per thread, static
//    sliding window W[15]+cur[8], taps hr[16] in registers
// Whole grid (1024 blocks x 256 thr) resident at once -> no ramp.

#define D_MODEL 1024
#define SEQ_LEN 4096
#define BATCH   8
#define JT      16
#define CH      128              // channels per block slab
#define PAIRS   (CH / 2)         // 64 float2 pairs per slab row
#define MP      (D_MODEL / 2)    // 512 pairs per full row
#define TW      64               // t per wave (private strip)
#define WPB     4                // waves per block
#define TBLK    (TW * WPB)       // 256 t per block

__global__ __launch_bounds__(256)
void k_fused(const float* __restrict__ x,
             const float* __restrict__ A,
             const float* __restrict__ B,
             const float* __restrict__ C,
             const float* __restrict__ Dv,
             float* __restrict__ y) {
    __shared__ float hs[JT][CH];       // 8 KB taps

    const int tid  = threadIdx.x;
    const int slab = blockIdx.y;
    const int b    = blockIdx.z;

    // ---- tap build: 4 lanes/channel, quad (DPP) shuffles, 2 passes ----
    {
        const int q  = tid & 3;        // owns w/A columns 4q..4q+3
        const int c0 = tid >> 2;       // 0..63
#pragma unroll
        for (int pass = 0; pass < 2; ++pass) {
            const int ch  = pass * 64 + c0;
            const int gch = slab * CH + ch;

            float4 Acol[16];           // Acol[s] = A[gch][s][4q..4q+3]
            const float* Ab = A + (size_t)gch * 256 + q * 4;
#pragma unroll
            for (int s = 0; s < 16; ++s)
                Acol[s] = *(const float4*)(Ab + s * 16);

            const float4 cv = *(const float4*)(C + (size_t)gch * 16 + q * 4);
            float4 w        = *(const float4*)(B + (size_t)gch * 16 + q * 4);

#pragma unroll
            for (int j = 0; j < JT; ++j) {
                float hp = w.x * cv.x + w.y * cv.y + w.z * cv.z + w.w * cv.w;
                hp += __shfl_xor(hp, 1, 4);
                hp += __shfl_xor(hp, 2, 4);
                if (q == 0) {
                    hs[j][ch] = (j == 0) ? hp + Dv[gch] : hp;
                }
                if (j < JT - 1) {
                    float4 wn = make_float4(0.f, 0.f, 0.f, 0.f);
#pragma unroll
                    for (int qq = 0; qq < 4; ++qq) {
                        float4 sg;
                        sg.x = __shfl(w.x, qq, 4);
                        sg.y = __shfl(w.y, qq, 4);
                        sg.z = __shfl(w.z, qq, 4);
                        sg.w = __shfl(w.w, qq, 4);
                        const int s0 = qq * 4;
                        wn.x += sg.x*Acol[s0].x + sg.y*Acol[s0+1].x + sg.z*Acol[s0+2].x + sg.w*Acol[s0+3].x;
                        wn.y += sg.x*Acol[s0].y + sg.y*Acol[s0+1].y + sg.z*Acol[s0+2].y + sg.w*Acol[s0+3].y;
                        wn.z += sg.x*Acol[s0].z + sg.y*Acol[s0+1].z + sg.z*Acol[s0+2].z + sg.w*Acol[s0+3].z;
                        wn.w += sg.x*Acol[s0].w + sg.y*Acol[s0+1].w + sg.z*Acol[s0+2].w + sg.w*Acol[s0+3].w;
                    }
                    w = wn;
                }
            }
        }
    }
    __syncthreads();   // the only barrier in the kernel

    // ---- conv: per-wave-private strip, barrier-free, static sliding window
    const int wv = tid >> 6;           // wave = strip index 0..3
    const int l  = tid & 63;           // channel pair within slab
    const int t0 = blockIdx.x * TBLK + wv * TW;

    const float2* xr = (const float2*)x + ((size_t)b * SEQ_LEN) * MP + slab * PAIRS + l;
    float2*       yr = (float2*)y       + ((size_t)b * SEQ_LEN) * MP + slab * PAIRS + l;

    float2 hr[JT];
#pragma unroll
    for (int j = 0; j < JT; ++j) hr[j] = *(const float2*)&hs[j][2 * l];

    // invariant at chunk start (base tb): W[i] = x[tb - 15 + i], i = 0..14
    float2 W[15];
    if (t0 != 0) {                     // wave-uniform branch
#pragma unroll
        for (int i = 0; i < 15; ++i) W[i] = xr[(size_t)(t0 - 15 + i) * MP];
    } else {
#pragma unroll
        for (int i = 0; i < 15; ++i) W[i] = make_float2(0.f, 0.f);
    }

    for (int cc = 0; cc < TW / 8; ++cc) {
        const int tb = t0 + cc * 8;

        float2 cur[8];                 // 8 independent loads in flight
#pragma unroll
        for (int i = 0; i < 8; ++i)
            cur[i] = xr[(size_t)(tb + i) * MP];

#pragma unroll
        for (int s = 0; s < 8; ++s) {
            float ax = 0.f, ay = 0.f;
#pragma unroll
            for (int j = 0; j < JT; ++j) {
                const int d = s - j;                       // compile-time
                const float2 xv = (d >= 0) ? cur[d] : W[15 + d];
                ax += hr[j].x * xv.x;
                ay += hr[j].y * xv.y;
            }
            yr[(size_t)(tb + s) * MP] = make_float2(ax, ay);
        }

        // slide window by 8 (all static moves)
#pragma unroll
        for (int i = 0; i < 7; ++i) W[i] = W[i + 8];
#pragma unroll
        for (int i = 7; i < 15; ++i) W[i] = cur[i - 7];
    }
}

// ---------------------------------------------------------------------------
extern "C" void kernel_launch(void* const* d_in, const int* in_sizes, int n_in,
                              void* d_out, int out_size, void* d_ws, size_t ws_size,
                              hipStream_t stream) {
    const float* x  = (const float*)d_in[0];
    const float* A  = (const float*)d_in[1];
    const float* B  = (const float*)d_in[2];
    const float* C  = (const float*)d_in[3];
    const float* Dv = (const float*)d_in[4];
    float* y = (float*)d_out;

    dim3 grid(SEQ_LEN / TBLK, D_MODEL / CH, BATCH);   // 16 x 8 x 8 = 1024
    k_fused<<<grid, 256, 0, stream>>>(x, A, B, C, Dv, y);
}